// Round 6
// baseline (642.472 us; speedup 1.0000x reference)
//
#include <hip/hip_runtime.h>
#include <math.h>

#define S 128
#define R 384
#define CM 256
#define CZ 128
#define H 8
#define D 32
#define INFB 1e9f
#define LN_EPS 1e-5f

typedef unsigned short u16;
typedef short bf16x8 __attribute__((ext_vector_type(8)));
typedef float f32x4 __attribute__((ext_vector_type(4)));

__device__ inline float wave_reduce_sum(float v) {
    #pragma unroll
    for (int o = 32; o > 0; o >>= 1) v += __shfl_xor(v, o, 64);
    return v;
}

__device__ inline u16 f2bf(float f) {
    union { float f; unsigned int u; } x; x.f = f;
    unsigned int r = x.u + 0x7fffu + ((x.u >> 16) & 1u);
    return (u16)(r >> 16);
}

// ---------------------------------------------------------------------------
// Weight prep: Wt[mi][n][k] = src_mi[k][n] as bf16; mi: 0=q(scaled),1=k,2=v,3=g,4=o
__global__ __launch_bounds__(256) void wprep_kernel(
    const float* __restrict__ wq, const float* __restrict__ wk,
    const float* __restrict__ wv, const float* __restrict__ wg,
    const float* __restrict__ wo, u16* __restrict__ Wt) {
    int n = blockIdx.x & 255;
    int mi = blockIdx.x >> 8;
    int kc = threadIdx.x;
    const float* src = mi == 0 ? wq : mi == 1 ? wk : mi == 2 ? wv
                     : mi == 3 ? wg : wo;
    float val = src[(size_t)kc * 256 + n];
    if (mi == 0) val *= 0.17677669529663687f;  // 1/sqrt(32)
    Wt[((size_t)mi * 256 + n) * 256 + kc] = f2bf(val);
}

// ---------------------------------------------------------------------------
// LN(m) -> A bf16 [S*R][256]. 4 rows per block, wave per row.
__global__ __launch_bounds__(256) void lnm_kernel(
    const float* __restrict__ m, const float* __restrict__ lnw,
    const float* __restrict__ lnb, u16* __restrict__ A) {
    int t = threadIdx.x;
    int wave = t >> 6, lane = t & 63;
    size_t row = (size_t)blockIdx.x * 4 + wave;
    float4 x = ((const float4*)(m + row * 256))[lane];
    float ss = wave_reduce_sum(x.x + x.y + x.z + x.w);
    float sq = wave_reduce_sum(x.x * x.x + x.y * x.y + x.z * x.z + x.w * x.w);
    float mu = ss * (1.0f / 256.0f);
    float var = sq * (1.0f / 256.0f) - mu * mu;
    float rstd = rsqrtf(var + LN_EPS);
    int c = lane * 4;
    ushort4 o4;
    o4.x = f2bf((x.x - mu) * rstd * lnw[c]     + lnb[c]);
    o4.y = f2bf((x.y - mu) * rstd * lnw[c + 1] + lnb[c + 1]);
    o4.z = f2bf((x.z - mu) * rstd * lnw[c + 2] + lnb[c + 2]);
    o4.w = f2bf((x.w - mu) * rstd * lnw[c + 3] + lnb[c + 3]);
    ((ushort4*)(A + row * 256))[lane] = o4;
}

// ---------------------------------------------------------------------------
// z_bias v3: algebra-folded, 16 lanes per (i,j) pair, 4 pairs per wave.
// OUTPUT IS TRANSPOSED: zbT[h][j=key][i=qrow] so attn can float4-load 4 qrows.
__global__ __launch_bounds__(256) void zbias_kernel(
    const float* __restrict__ z, const float* __restrict__ lnw,
    const float* __restrict__ lnb, const float* __restrict__ wz,
    float* __restrict__ zbias) {
    int t = threadIdx.x;
    int lane = t & 63, wave = t >> 6;
    int g = lane >> 4, u = lane & 15;  // pair-group, lane-in-group
    int c0 = u * 8;                    // this lane's first channel

    float lw[8], lb[8];
    {
        float4 a = *(const float4*)(lnw + c0);
        float4 b = *(const float4*)(lnw + c0 + 4);
        lw[0]=a.x; lw[1]=a.y; lw[2]=a.z; lw[3]=a.w;
        lw[4]=b.x; lw[5]=b.y; lw[6]=b.z; lw[7]=b.w;
        float4 c = *(const float4*)(lnb + c0);
        float4 d = *(const float4*)(lnb + c0 + 4);
        lb[0]=c.x; lb[1]=c.y; lb[2]=c.z; lb[3]=c.w;
        lb[4]=d.x; lb[5]=d.y; lb[6]=d.z; lb[7]=d.w;
    }
    float uw[8][8];
    float bwp[8];
    #pragma unroll
    for (int h = 0; h < 8; ++h) bwp[h] = 0.f;
    #pragma unroll
    for (int i = 0; i < 8; ++i) {
        float4 w0 = *(const float4*)(wz + (size_t)(c0 + i) * 8);
        float4 w1 = *(const float4*)(wz + (size_t)(c0 + i) * 8 + 4);
        uw[i][0] = lw[i] * w0.x; uw[i][1] = lw[i] * w0.y;
        uw[i][2] = lw[i] * w0.z; uw[i][3] = lw[i] * w0.w;
        uw[i][4] = lw[i] * w1.x; uw[i][5] = lw[i] * w1.y;
        uw[i][6] = lw[i] * w1.z; uw[i][7] = lw[i] * w1.w;
        bwp[0] = fmaf(lb[i], w0.x, bwp[0]); bwp[1] = fmaf(lb[i], w0.y, bwp[1]);
        bwp[2] = fmaf(lb[i], w0.z, bwp[2]); bwp[3] = fmaf(lb[i], w0.w, bwp[3]);
        bwp[4] = fmaf(lb[i], w1.x, bwp[4]); bwp[5] = fmaf(lb[i], w1.y, bwp[5]);
        bwp[6] = fmaf(lb[i], w1.z, bwp[6]); bwp[7] = fmaf(lb[i], w1.w, bwp[7]);
    }

    const int nwaves = gridDim.x * 4;           // 2304*4 = 9216
    int wid = blockIdx.x * 4 + wave;
    #pragma unroll 1
    for (int it = 0; it < 4; ++it) {            // 9216*4*4 = 147456 pairs
        int p = (wid + it * nwaves) * 4 + g;
        const float* zp = z + (size_t)p * CZ + c0;
        float4 z0 = *(const float4*)zp;
        float4 z1 = *(const float4*)(zp + 4);
        float x[8] = {z0.x, z0.y, z0.z, z0.w, z1.x, z1.y, z1.z, z1.w};
        float ss = 0.f, sq = 0.f;
        #pragma unroll
        for (int i = 0; i < 8; ++i) { ss += x[i]; sq = fmaf(x[i], x[i], sq); }
        #pragma unroll
        for (int o = 1; o < 16; o <<= 1) {
            ss += __shfl_xor(ss, o, 64);
            sq += __shfl_xor(sq, o, 64);
        }
        float mu = ss * (1.0f / CZ);
        float var = sq * (1.0f / CZ) - mu * mu;
        float rstd = rsqrtf(var + LN_EPS);
        float ph[8];
        #pragma unroll
        for (int h = 0; h < 8; ++h) ph[h] = bwp[h];
        #pragma unroll
        for (int i = 0; i < 8; ++i) {
            float ti = (x[i] - mu) * rstd;
            #pragma unroll
            for (int h = 0; h < 8; ++h) ph[h] = fmaf(ti, uw[i][h], ph[h]);
        }
        #pragma unroll
        for (int h = 0; h < 8; ++h) {
            #pragma unroll
            for (int o = 1; o < 16; o <<= 1) ph[h] += __shfl_xor(ph[h], o, 64);
        }
        if (u < 8) {
            float outv = ph[0];
            if (u == 1) outv = ph[1];
            if (u == 2) outv = ph[2];
            if (u == 3) outv = ph[3];
            if (u == 4) outv = ph[4];
            if (u == 5) outv = ph[5];
            if (u == 6) outv = ph[6];
            if (u == 7) outv = ph[7];
            int i = p / R;           // q row
            int j = p - i * R;       // key
            zbias[(size_t)u * (R * R) + (size_t)j * R + i] = outv;
        }
    }
}

// ---------------------------------------------------------------------------
// qkvg GEMM: M=49152, K=256, one weight matrix per blockIdx.y.
// nb: 0=q, 1=k (row-major bf16), 2=v (written TRANSPOSED as vT[s][h][d][key]),
// 3=g (fp32 + sigmoid).
__global__ __launch_bounds__(512) void qkvg_gemm(
    const u16* __restrict__ A, const u16* __restrict__ Wt,
    const float* __restrict__ bg,
    u16* __restrict__ q, u16* __restrict__ k, u16* __restrict__ vT,
    float* __restrict__ g) {
    int nb = blockIdx.y;
    size_t row0 = (size_t)blockIdx.x * 128;
    int t = threadIdx.x, lane = t & 63, wave = t >> 6;
    int l15 = lane & 15, l4 = lane >> 4;
    int wm = (wave >> 2) * 64, wn = (wave & 3) * 64;
    const u16* B = Wt + (size_t)nb * 256 * 256;
    const u16* Ab = A + (row0 + wm + l15) * 256 + l4 * 8;
    const u16* Bb = B + (size_t)(wn + l15) * 256 + l4 * 8;

    f32x4 acc[4][4];
    #pragma unroll
    for (int mt = 0; mt < 4; ++mt)
        #pragma unroll
        for (int nt = 0; nt < 4; ++nt)
            acc[mt][nt] = (f32x4){0.f, 0.f, 0.f, 0.f};

    #pragma unroll
    for (int kk = 0; kk < 8; ++kk) {
        bf16x8 af[4], bfr[4];
        #pragma unroll
        for (int mt = 0; mt < 4; ++mt)
            af[mt] = *(const bf16x8*)(Ab + (size_t)mt * 16 * 256 + kk * 32);
        #pragma unroll
        for (int nt = 0; nt < 4; ++nt)
            bfr[nt] = *(const bf16x8*)(Bb + (size_t)nt * 16 * 256 + kk * 32);
        #pragma unroll
        for (int mt = 0; mt < 4; ++mt)
            #pragma unroll
            for (int nt = 0; nt < 4; ++nt)
                acc[mt][nt] = __builtin_amdgcn_mfma_f32_16x16x32_bf16(
                    af[mt], bfr[nt], acc[mt][nt], 0, 0, 0);
    }

    if (nb == 3) {
        #pragma unroll
        for (int nt = 0; nt < 4; ++nt) {
            int col = wn + nt * 16 + l15;
            float bgv = bg[col];
            #pragma unroll
            for (int mt = 0; mt < 4; ++mt)
                #pragma unroll
                for (int r = 0; r < 4; ++r) {
                    size_t row = row0 + wm + mt * 16 + l4 * 4 + r;
                    g[row * 256 + col] =
                        1.0f / (1.0f + __expf(-(acc[mt][nt][r] + bgv)));
                }
        }
    } else if (nb == 2) {
        // vT[((s*8 + h)*32 + d)*384 + rres] ; 4 consecutive rres -> ushort4
        #pragma unroll
        for (int nt = 0; nt < 4; ++nt) {
            int col = wn + nt * 16 + l15;
            int hh = col >> 5, dd = col & 31;
            #pragma unroll
            for (int mt = 0; mt < 4; ++mt) {
                size_t row = row0 + wm + mt * 16 + l4 * 4;  // first of 4
                int ss = (int)(row / 384);
                int rr = (int)(row - (size_t)ss * 384);
                ushort4 pk;
                pk.x = f2bf(acc[mt][nt][0]);
                pk.y = f2bf(acc[mt][nt][1]);
                pk.z = f2bf(acc[mt][nt][2]);
                pk.w = f2bf(acc[mt][nt][3]);
                *(ushort4*)(vT + ((size_t)(ss * 8 + hh) * 32 + dd) * 384 + rr) = pk;
            }
        }
    } else {
        u16* dst = nb == 0 ? q : k;
        #pragma unroll
        for (int nt = 0; nt < 4; ++nt) {
            int col = wn + nt * 16 + l15;
            #pragma unroll
            for (int mt = 0; mt < 4; ++mt)
                #pragma unroll
                for (int r = 0; r < 4; ++r) {
                    size_t row = row0 + wm + mt * 16 + l4 * 4 + r;
                    dst[row * 256 + col] = f2bf(acc[mt][nt][r]);
                }
        }
    }
}

// ---------------------------------------------------------------------------
// out GEMM: M=49152, N=256, K=256; A = o (bf16), +b_o, fp32 out.
__global__ __launch_bounds__(512) void out_gemm(
    const u16* __restrict__ A, const u16* __restrict__ Wt,
    const float* __restrict__ bo, float* __restrict__ out) {
    size_t row0 = (size_t)blockIdx.x * 128;
    int t = threadIdx.x, lane = t & 63, wave = t >> 6;
    int l15 = lane & 15, l4 = lane >> 4;
    int wm = (wave >> 2) * 64, wn = (wave & 3) * 64;
    const u16* Ab = A + (row0 + wm + l15) * 256 + l4 * 8;
    const u16* Bb = Wt + (size_t)(wn + l15) * 256 + l4 * 8;

    f32x4 acc[4][4];
    #pragma unroll
    for (int mt = 0; mt < 4; ++mt)
        #pragma unroll
        for (int nt = 0; nt < 4; ++nt)
            acc[mt][nt] = (f32x4){0.f, 0.f, 0.f, 0.f};

    #pragma unroll
    for (int kk = 0; kk < 8; ++kk) {
        bf16x8 af[4], bfr[4];
        #pragma unroll
        for (int mt = 0; mt < 4; ++mt)
            af[mt] = *(const bf16x8*)(Ab + (size_t)mt * 16 * 256 + kk * 32);
        #pragma unroll
        for (int nt = 0; nt < 4; ++nt)
            bfr[nt] = *(const bf16x8*)(Bb + (size_t)nt * 16 * 256 + kk * 32);
        #pragma unroll
        for (int mt = 0; mt < 4; ++mt)
            #pragma unroll
            for (int nt = 0; nt < 4; ++nt)
                acc[mt][nt] = __builtin_amdgcn_mfma_f32_16x16x32_bf16(
                    af[mt], bfr[nt], acc[mt][nt], 0, 0, 0);
    }

    #pragma unroll
    for (int nt = 0; nt < 4; ++nt) {
        int col = wn + nt * 16 + l15;
        float bov = bo[col];
        #pragma unroll
        for (int mt = 0; mt < 4; ++mt)
            #pragma unroll
            for (int r = 0; r < 4; ++r) {
                size_t row = row0 + wm + mt * 16 + l4 * 4 + r;
                out[row * 256 + col] = acc[mt][nt][r] + bov;
            }
    }
}

// ---------------------------------------------------------------------------
// Attention v4: MFMA bf16, one block (512 thr, 8 waves) per (s, h).
// No V staging, no barriers. V B-frags from global vT[s][h][d][key] (L2-hot).
// zb loads are float4 from transposed zbT[h][key][qrow]. LDS = Psh only.
__global__ __launch_bounds__(512, 8) void attn_kernel(
    const u16* __restrict__ q, const u16* __restrict__ k,
    const u16* __restrict__ vT, const float* __restrict__ g,
    const float* __restrict__ mask, const float* __restrict__ zbT,
    u16* __restrict__ o) {
    int h = blockIdx.x, s = blockIdx.y;
    int t = threadIdx.x;
    int lane = t & 63, wave = t >> 6;
    int l15 = lane & 15, l4 = lane >> 4;

    __shared__ __attribute__((aligned(16))) u16 Psh[8 * 48 * 32];

    size_t base = ((size_t)s * R) * 256 + (size_t)h * 32;  // bf16 elem offset
    const u16* vbase = vT + ((size_t)(s * H + h) * 32) * 384;

    int wq0 = wave * 48;
    bf16x8 qf[3];
    #pragma unroll
    for (int rt = 0; rt < 3; ++rt)
        qf[rt] = *(const bf16x8*)(q + base +
                                  (size_t)(wq0 + rt * 16 + l15) * 256 + l4 * 8);

    f32x4 oacc[3][2];
    #pragma unroll
    for (int rt = 0; rt < 3; ++rt)
        #pragma unroll
        for (int dt = 0; dt < 2; ++dt)
            oacc[rt][dt] = (f32x4){0.f, 0.f, 0.f, 0.f};
    float pden[3][4] = {};

    const float* zbh = zbT + (size_t)h * R * R;  // [key][qrow]
    const int pbase = wave * 1536;

    for (int kt = 0; kt < R; kt += 32) {
        bf16x8 kf[2];
        float mv[2];
        #pragma unroll
        for (int ct = 0; ct < 2; ++ct) {
            int key = kt + ct * 16 + l15;
            kf[ct] = *(const bf16x8*)(k + base + (size_t)key * 256 + l4 * 8);
            mv[ct] = INFB * (mask[(size_t)s * R + key] - 1.0f);
        }

        const f32x4 z4 = {0.f, 0.f, 0.f, 0.f};
        f32x4 sfr[3][2];
        #pragma unroll
        for (int rt = 0; rt < 3; ++rt)
            #pragma unroll
            for (int ct = 0; ct < 2; ++ct)
                sfr[rt][ct] = __builtin_amdgcn_mfma_f32_16x16x32_bf16(
                    qf[rt], kf[ct], z4, 0, 0, 0);

        #pragma unroll
        for (int rt = 0; rt < 3; ++rt) {
            #pragma unroll
            for (int ct = 0; ct < 2; ++ct) {
                // 4 consecutive q-rows for this lane's key -> one float4
                f32x4 zv4 = *(const f32x4*)(zbh +
                    (size_t)(kt + ct * 16 + l15) * R + wq0 + rt * 16 + l4 * 4);
                #pragma unroll
                for (int r = 0; r < 4; ++r) {
                    int row = rt * 16 + l4 * 4 + r;
                    float e = __expf(sfr[rt][ct][r] + mv[ct] + zv4[r]);
                    pden[rt][r] += e;
                    int ei = (row * 32 + ct * 16 + l15) ^ (((row >> 2) & 3) << 4);
                    Psh[pbase + ei] = f2bf(e);
                }
            }
        }

        #pragma unroll
        for (int rt = 0; rt < 3; ++rt) {
            int row = rt * 16 + l15;
            int ei = (row * 32 + l4 * 8) ^ (((row >> 2) & 3) << 4);
            bf16x8 pa = *(const bf16x8*)&Psh[pbase + ei];
            #pragma unroll
            for (int dt = 0; dt < 2; ++dt) {
                bf16x8 vbf = *(const bf16x8*)(vbase +
                    (size_t)(dt * 16 + l15) * 384 + kt + l4 * 8);
                oacc[rt][dt] = __builtin_amdgcn_mfma_f32_16x16x32_bf16(
                    pa, vbf, oacc[rt][dt], 0, 0, 0);
            }
        }
    }

    #pragma unroll
    for (int rt = 0; rt < 3; ++rt)
        #pragma unroll
        for (int r = 0; r < 4; ++r) {
            float d = pden[rt][r];
            d += __shfl_xor(d, 1, 64);
            d += __shfl_xor(d, 2, 64);
            d += __shfl_xor(d, 4, 64);
            d += __shfl_xor(d, 8, 64);
            pden[rt][r] = d;
        }

    #pragma unroll
    for (int rt = 0; rt < 3; ++rt) {
        #pragma unroll
        for (int r = 0; r < 4; ++r) {
            float inv = 1.0f / pden[rt][r];
            int qrow = wq0 + rt * 16 + l4 * 4 + r;
            #pragma unroll
            for (int dt = 0; dt < 2; ++dt) {
                size_t off = base + (size_t)qrow * 256 + dt * 16 + l15;
                o[off] = f2bf(oacc[rt][dt][r] * inv * g[off]);
            }
        }
    }
}

extern "C" void kernel_launch(void* const* d_in, const int* in_sizes, int n_in,
                              void* d_out, int out_size, void* d_ws, size_t ws_size,
                              hipStream_t stream) {
    (void)in_sizes; (void)n_in; (void)out_size; (void)ws_size;
    const float* m      = (const float*)d_in[0];
    const float* z      = (const float*)d_in[1];
    const float* mask   = (const float*)d_in[2];
    const float* ln_m_w = (const float*)d_in[3];
    const float* ln_m_b = (const float*)d_in[4];
    const float* ln_z_w = (const float*)d_in[5];
    const float* ln_z_b = (const float*)d_in[6];
    const float* w_z    = (const float*)d_in[7];
    const float* w_q    = (const float*)d_in[8];
    const float* w_k    = (const float*)d_in[9];
    const float* w_v    = (const float*)d_in[10];
    const float* w_g    = (const float*)d_in[11];
    const float* b_g    = (const float*)d_in[12];
    const float* w_o    = (const float*)d_in[13];
    const float* b_o    = (const float*)d_in[14];
    float* out = (float*)d_out;
    char* wsb = (char*)d_ws;

    const size_t NR = (size_t)S * R;  // 49152 rows
    u16*   A   = (u16*)wsb;                      wsb += NR * 256 * 2;
    u16*   q   = (u16*)wsb;                      wsb += NR * 256 * 2;
    u16*   k   = (u16*)wsb;                      wsb += NR * 256 * 2;
    u16*   vT  = (u16*)wsb;                      wsb += NR * 256 * 2;
    u16*   o   = (u16*)wsb;                      wsb += NR * 256 * 2;
    float* g   = (float*)wsb;                    wsb += NR * 256 * 4;
    float* zbT = (float*)wsb;                    wsb += (size_t)H * R * R * 4;
    u16*   Wt  = (u16*)wsb;                      wsb += (size_t)5 * 256 * 256 * 2;

    wprep_kernel<<<5 * 256, 256, 0, stream>>>(w_q, w_k, w_v, w_g, w_o, Wt);
    lnm_kernel<<<NR / 4, 256, 0, stream>>>(m, ln_m_w, ln_m_b, A);
    zbias_kernel<<<2304, 256, 0, stream>>>(z, ln_z_w, ln_z_b, w_z, zbT);
    qkvg_gemm<<<dim3(NR / 128, 4), 512, 0, stream>>>(A, Wt, b_g, q, k, vT, g);
    attn_kernel<<<dim3(H, S), 512, 0, stream>>>(q, k, vT, g, mask, zbT, o);
    out_gemm<<<NR / 128, 512, 0, stream>>>(o, Wt + (size_t)4 * 256 * 256, b_o, out);
}

// Round 7
// 348.574 us; speedup vs baseline: 1.8431x; 1.8431x over previous
//
#include <hip/hip_runtime.h>
#include <math.h>

#define S 128
#define R 384
#define CM 256
#define CZ 128
#define H 8
#define D 32
#define INFB 1e9f
#define LN_EPS 1e-5f

typedef unsigned short u16;
typedef short bf16x8 __attribute__((ext_vector_type(8)));
typedef float f32x4 __attribute__((ext_vector_type(4)));

__device__ inline float wave_reduce_sum(float v) {
    #pragma unroll
    for (int o = 32; o > 0; o >>= 1) v += __shfl_xor(v, o, 64);
    return v;
}

__device__ inline u16 f2bf(float f) {
    union { float f; unsigned int u; } x; x.f = f;
    unsigned int r = x.u + 0x7fffu + ((x.u >> 16) & 1u);
    return (u16)(r >> 16);
}

// ---------------------------------------------------------------------------
// Weight prep: Wt[mi][n][k] = src_mi[k][n] as bf16; mi: 0=q(scaled),1=k,2=v,3=g,4=o
__global__ __launch_bounds__(256) void wprep_kernel(
    const float* __restrict__ wq, const float* __restrict__ wk,
    const float* __restrict__ wv, const float* __restrict__ wg,
    const float* __restrict__ wo, u16* __restrict__ Wt) {
    int n = blockIdx.x & 255;
    int mi = blockIdx.x >> 8;
    int kc = threadIdx.x;
    const float* src = mi == 0 ? wq : mi == 1 ? wk : mi == 2 ? wv
                     : mi == 3 ? wg : wo;
    float val = src[(size_t)kc * 256 + n];
    if (mi == 0) val *= 0.17677669529663687f;  // 1/sqrt(32)
    Wt[((size_t)mi * 256 + n) * 256 + kc] = f2bf(val);
}

// ---------------------------------------------------------------------------
// LN(m) -> A bf16 [S*R][256]. 4 rows per block, wave per row.
__global__ __launch_bounds__(256) void lnm_kernel(
    const float* __restrict__ m, const float* __restrict__ lnw,
    const float* __restrict__ lnb, u16* __restrict__ A) {
    int t = threadIdx.x;
    int wave = t >> 6, lane = t & 63;
    size_t row = (size_t)blockIdx.x * 4 + wave;
    float4 x = ((const float4*)(m + row * 256))[lane];
    float ss = wave_reduce_sum(x.x + x.y + x.z + x.w);
    float sq = wave_reduce_sum(x.x * x.x + x.y * x.y + x.z * x.z + x.w * x.w);
    float mu = ss * (1.0f / 256.0f);
    float var = sq * (1.0f / 256.0f) - mu * mu;
    float rstd = rsqrtf(var + LN_EPS);
    int c = lane * 4;
    ushort4 o4;
    o4.x = f2bf((x.x - mu) * rstd * lnw[c]     + lnb[c]);
    o4.y = f2bf((x.y - mu) * rstd * lnw[c + 1] + lnb[c + 1]);
    o4.z = f2bf((x.z - mu) * rstd * lnw[c + 2] + lnb[c + 2]);
    o4.w = f2bf((x.w - mu) * rstd * lnw[c + 3] + lnb[c + 3]);
    ((ushort4*)(A + row * 256))[lane] = o4;
}

// ---------------------------------------------------------------------------
// z_bias v3: algebra-folded, 16 lanes per (i,j) pair, 4 pairs per wave.
// OUTPUT IS TRANSPOSED: zbT[h][j=key][i=qrow] so attn can float4-load 4 qrows.
__global__ __launch_bounds__(256) void zbias_kernel(
    const float* __restrict__ z, const float* __restrict__ lnw,
    const float* __restrict__ lnb, const float* __restrict__ wz,
    float* __restrict__ zbias) {
    int t = threadIdx.x;
    int lane = t & 63, wave = t >> 6;
    int g = lane >> 4, u = lane & 15;  // pair-group, lane-in-group
    int c0 = u * 8;                    // this lane's first channel

    float lw[8], lb[8];
    {
        float4 a = *(const float4*)(lnw + c0);
        float4 b = *(const float4*)(lnw + c0 + 4);
        lw[0]=a.x; lw[1]=a.y; lw[2]=a.z; lw[3]=a.w;
        lw[4]=b.x; lw[5]=b.y; lw[6]=b.z; lw[7]=b.w;
        float4 c = *(const float4*)(lnb + c0);
        float4 d = *(const float4*)(lnb + c0 + 4);
        lb[0]=c.x; lb[1]=c.y; lb[2]=c.z; lb[3]=c.w;
        lb[4]=d.x; lb[5]=d.y; lb[6]=d.z; lb[7]=d.w;
    }
    float uw[8][8];
    float bwp[8];
    #pragma unroll
    for (int h = 0; h < 8; ++h) bwp[h] = 0.f;
    #pragma unroll
    for (int i = 0; i < 8; ++i) {
        float4 w0 = *(const float4*)(wz + (size_t)(c0 + i) * 8);
        float4 w1 = *(const float4*)(wz + (size_t)(c0 + i) * 8 + 4);
        uw[i][0] = lw[i] * w0.x; uw[i][1] = lw[i] * w0.y;
        uw[i][2] = lw[i] * w0.z; uw[i][3] = lw[i] * w0.w;
        uw[i][4] = lw[i] * w1.x; uw[i][5] = lw[i] * w1.y;
        uw[i][6] = lw[i] * w1.z; uw[i][7] = lw[i] * w1.w;
        bwp[0] = fmaf(lb[i], w0.x, bwp[0]); bwp[1] = fmaf(lb[i], w0.y, bwp[1]);
        bwp[2] = fmaf(lb[i], w0.z, bwp[2]); bwp[3] = fmaf(lb[i], w0.w, bwp[3]);
        bwp[4] = fmaf(lb[i], w1.x, bwp[4]); bwp[5] = fmaf(lb[i], w1.y, bwp[5]);
        bwp[6] = fmaf(lb[i], w1.z, bwp[6]); bwp[7] = fmaf(lb[i], w1.w, bwp[7]);
    }

    const int nwaves = gridDim.x * 4;           // 2304*4 = 9216
    int wid = blockIdx.x * 4 + wave;
    #pragma unroll 1
    for (int it = 0; it < 4; ++it) {            // 9216*4*4 = 147456 pairs
        int p = (wid + it * nwaves) * 4 + g;
        const float* zp = z + (size_t)p * CZ + c0;
        float4 z0 = *(const float4*)zp;
        float4 z1 = *(const float4*)(zp + 4);
        float x[8] = {z0.x, z0.y, z0.z, z0.w, z1.x, z1.y, z1.z, z1.w};
        float ss = 0.f, sq = 0.f;
        #pragma unroll
        for (int i = 0; i < 8; ++i) { ss += x[i]; sq = fmaf(x[i], x[i], sq); }
        #pragma unroll
        for (int o = 1; o < 16; o <<= 1) {
            ss += __shfl_xor(ss, o, 64);
            sq += __shfl_xor(sq, o, 64);
        }
        float mu = ss * (1.0f / CZ);
        float var = sq * (1.0f / CZ) - mu * mu;
        float rstd = rsqrtf(var + LN_EPS);
        float ph[8];
        #pragma unroll
        for (int h = 0; h < 8; ++h) ph[h] = bwp[h];
        #pragma unroll
        for (int i = 0; i < 8; ++i) {
            float ti = (x[i] - mu) * rstd;
            #pragma unroll
            for (int h = 0; h < 8; ++h) ph[h] = fmaf(ti, uw[i][h], ph[h]);
        }
        #pragma unroll
        for (int h = 0; h < 8; ++h) {
            #pragma unroll
            for (int o = 1; o < 16; o <<= 1) ph[h] += __shfl_xor(ph[h], o, 64);
        }
        if (u < 8) {
            float outv = ph[0];
            if (u == 1) outv = ph[1];
            if (u == 2) outv = ph[2];
            if (u == 3) outv = ph[3];
            if (u == 4) outv = ph[4];
            if (u == 5) outv = ph[5];
            if (u == 6) outv = ph[6];
            if (u == 7) outv = ph[7];
            int i = p / R;           // q row
            int j = p - i * R;       // key
            zbias[(size_t)u * (R * R) + (size_t)j * R + i] = outv;
        }
    }
}

// ---------------------------------------------------------------------------
// qkvg GEMM: M=49152, K=256, one weight matrix per blockIdx.y.
// nb: 0=q, 1=k (row-major bf16), 2=v (written TRANSPOSED as vT[s][h][d][key]),
// 3=g (fp32 + sigmoid).
__global__ __launch_bounds__(512) void qkvg_gemm(
    const u16* __restrict__ A, const u16* __restrict__ Wt,
    const float* __restrict__ bg,
    u16* __restrict__ q, u16* __restrict__ k, u16* __restrict__ vT,
    float* __restrict__ g) {
    int nb = blockIdx.y;
    size_t row0 = (size_t)blockIdx.x * 128;
    int t = threadIdx.x, lane = t & 63, wave = t >> 6;
    int l15 = lane & 15, l4 = lane >> 4;
    int wm = (wave >> 2) * 64, wn = (wave & 3) * 64;
    const u16* B = Wt + (size_t)nb * 256 * 256;
    const u16* Ab = A + (row0 + wm + l15) * 256 + l4 * 8;
    const u16* Bb = B + (size_t)(wn + l15) * 256 + l4 * 8;

    f32x4 acc[4][4];
    #pragma unroll
    for (int mt = 0; mt < 4; ++mt)
        #pragma unroll
        for (int nt = 0; nt < 4; ++nt)
            acc[mt][nt] = (f32x4){0.f, 0.f, 0.f, 0.f};

    #pragma unroll
    for (int kk = 0; kk < 8; ++kk) {
        bf16x8 af[4], bfr[4];
        #pragma unroll
        for (int mt = 0; mt < 4; ++mt)
            af[mt] = *(const bf16x8*)(Ab + (size_t)mt * 16 * 256 + kk * 32);
        #pragma unroll
        for (int nt = 0; nt < 4; ++nt)
            bfr[nt] = *(const bf16x8*)(Bb + (size_t)nt * 16 * 256 + kk * 32);
        #pragma unroll
        for (int mt = 0; mt < 4; ++mt)
            #pragma unroll
            for (int nt = 0; nt < 4; ++nt)
                acc[mt][nt] = __builtin_amdgcn_mfma_f32_16x16x32_bf16(
                    af[mt], bfr[nt], acc[mt][nt], 0, 0, 0);
    }

    if (nb == 3) {
        #pragma unroll
        for (int nt = 0; nt < 4; ++nt) {
            int col = wn + nt * 16 + l15;
            float bgv = bg[col];
            #pragma unroll
            for (int mt = 0; mt < 4; ++mt)
                #pragma unroll
                for (int r = 0; r < 4; ++r) {
                    size_t row = row0 + wm + mt * 16 + l4 * 4 + r;
                    g[row * 256 + col] =
                        1.0f / (1.0f + __expf(-(acc[mt][nt][r] + bgv)));
                }
        }
    } else if (nb == 2) {
        // vT[((s*8 + h)*32 + d)*384 + rres] ; 4 consecutive rres -> ushort4
        #pragma unroll
        for (int nt = 0; nt < 4; ++nt) {
            int col = wn + nt * 16 + l15;
            int hh = col >> 5, dd = col & 31;
            #pragma unroll
            for (int mt = 0; mt < 4; ++mt) {
                size_t row = row0 + wm + mt * 16 + l4 * 4;  // first of 4
                int ss = (int)(row / 384);
                int rr = (int)(row - (size_t)ss * 384);
                ushort4 pk;
                pk.x = f2bf(acc[mt][nt][0]);
                pk.y = f2bf(acc[mt][nt][1]);
                pk.z = f2bf(acc[mt][nt][2]);
                pk.w = f2bf(acc[mt][nt][3]);
                *(ushort4*)(vT + ((size_t)(ss * 8 + hh) * 32 + dd) * 384 + rr) = pk;
            }
        }
    } else {
        u16* dst = nb == 0 ? q : k;
        #pragma unroll
        for (int nt = 0; nt < 4; ++nt) {
            int col = wn + nt * 16 + l15;
            #pragma unroll
            for (int mt = 0; mt < 4; ++mt)
                #pragma unroll
                for (int r = 0; r < 4; ++r) {
                    size_t row = row0 + wm + mt * 16 + l4 * 4 + r;
                    dst[row * 256 + col] = f2bf(acc[mt][nt][r]);
                }
        }
    }
}

// ---------------------------------------------------------------------------
// out GEMM: M=49152, N=256, K=256; A = o (bf16), +b_o, fp32 out.
__global__ __launch_bounds__(512) void out_gemm(
    const u16* __restrict__ A, const u16* __restrict__ Wt,
    const float* __restrict__ bo, float* __restrict__ out) {
    size_t row0 = (size_t)blockIdx.x * 128;
    int t = threadIdx.x, lane = t & 63, wave = t >> 6;
    int l15 = lane & 15, l4 = lane >> 4;
    int wm = (wave >> 2) * 64, wn = (wave & 3) * 64;
    const u16* Ab = A + (row0 + wm + l15) * 256 + l4 * 8;
    const u16* Bb = Wt + (size_t)(wn + l15) * 256 + l4 * 8;

    f32x4 acc[4][4];
    #pragma unroll
    for (int mt = 0; mt < 4; ++mt)
        #pragma unroll
        for (int nt = 0; nt < 4; ++nt)
            acc[mt][nt] = (f32x4){0.f, 0.f, 0.f, 0.f};

    #pragma unroll
    for (int kk = 0; kk < 8; ++kk) {
        bf16x8 af[4], bfr[4];
        #pragma unroll
        for (int mt = 0; mt < 4; ++mt)
            af[mt] = *(const bf16x8*)(Ab + (size_t)mt * 16 * 256 + kk * 32);
        #pragma unroll
        for (int nt = 0; nt < 4; ++nt)
            bfr[nt] = *(const bf16x8*)(Bb + (size_t)nt * 16 * 256 + kk * 32);
        #pragma unroll
        for (int mt = 0; mt < 4; ++mt)
            #pragma unroll
            for (int nt = 0; nt < 4; ++nt)
                acc[mt][nt] = __builtin_amdgcn_mfma_f32_16x16x32_bf16(
                    af[mt], bfr[nt], acc[mt][nt], 0, 0, 0);
    }

    #pragma unroll
    for (int nt = 0; nt < 4; ++nt) {
        int col = wn + nt * 16 + l15;
        float bov = bo[col];
        #pragma unroll
        for (int mt = 0; mt < 4; ++mt)
            #pragma unroll
            for (int r = 0; r < 4; ++r) {
                size_t row = row0 + wm + mt * 16 + l4 * 4 + r;
                out[row * 256 + col] = acc[mt][nt][r] + bov;
            }
    }
}

// ---------------------------------------------------------------------------
// Attention v5: same as v4 but WITHOUT the min-waves launch-bounds clause
// (v4's (512,8) capped VGPR -> massive scratch spill: WRITE_SIZE 663MB).
__global__ __launch_bounds__(512) void attn_kernel(
    const u16* __restrict__ q, const u16* __restrict__ k,
    const u16* __restrict__ vT, const float* __restrict__ g,
    const float* __restrict__ mask, const float* __restrict__ zbT,
    u16* __restrict__ o) {
    int h = blockIdx.x, s = blockIdx.y;
    int t = threadIdx.x;
    int lane = t & 63, wave = t >> 6;
    int l15 = lane & 15, l4 = lane >> 4;

    __shared__ __attribute__((aligned(16))) u16 Psh[8 * 48 * 32];

    size_t base = ((size_t)s * R) * 256 + (size_t)h * 32;  // bf16 elem offset
    const u16* vbase = vT + ((size_t)(s * H + h) * 32) * 384;

    int wq0 = wave * 48;
    bf16x8 qf[3];
    #pragma unroll
    for (int rt = 0; rt < 3; ++rt)
        qf[rt] = *(const bf16x8*)(q + base +
                                  (size_t)(wq0 + rt * 16 + l15) * 256 + l4 * 8);

    f32x4 oacc[3][2];
    #pragma unroll
    for (int rt = 0; rt < 3; ++rt)
        #pragma unroll
        for (int dt = 0; dt < 2; ++dt)
            oacc[rt][dt] = (f32x4){0.f, 0.f, 0.f, 0.f};
    float pden[3][4] = {};

    const float* zbh = zbT + (size_t)h * R * R;  // [key][qrow]
    const int pbase = wave * 1536;

    for (int kt = 0; kt < R; kt += 32) {
        bf16x8 kf[2];
        float mv[2];
        #pragma unroll
        for (int ct = 0; ct < 2; ++ct) {
            int key = kt + ct * 16 + l15;
            kf[ct] = *(const bf16x8*)(k + base + (size_t)key * 256 + l4 * 8);
            mv[ct] = INFB * (mask[(size_t)s * R + key] - 1.0f);
        }

        const f32x4 z4 = {0.f, 0.f, 0.f, 0.f};
        f32x4 sfr[3][2];
        #pragma unroll
        for (int rt = 0; rt < 3; ++rt)
            #pragma unroll
            for (int ct = 0; ct < 2; ++ct)
                sfr[rt][ct] = __builtin_amdgcn_mfma_f32_16x16x32_bf16(
                    qf[rt], kf[ct], z4, 0, 0, 0);

        #pragma unroll
        for (int rt = 0; rt < 3; ++rt) {
            #pragma unroll
            for (int ct = 0; ct < 2; ++ct) {
                // 4 consecutive q-rows for this lane's key -> one float4
                f32x4 zv4 = *(const f32x4*)(zbh +
                    (size_t)(kt + ct * 16 + l15) * R + wq0 + rt * 16 + l4 * 4);
                #pragma unroll
                for (int r = 0; r < 4; ++r) {
                    int row = rt * 16 + l4 * 4 + r;
                    float e = __expf(sfr[rt][ct][r] + mv[ct] + zv4[r]);
                    pden[rt][r] += e;
                    int ei = (row * 32 + ct * 16 + l15) ^ (((row >> 2) & 3) << 4);
                    Psh[pbase + ei] = f2bf(e);
                }
            }
        }

        #pragma unroll
        for (int rt = 0; rt < 3; ++rt) {
            int row = rt * 16 + l15;
            int ei = (row * 32 + l4 * 8) ^ (((row >> 2) & 3) << 4);
            bf16x8 pa = *(const bf16x8*)&Psh[pbase + ei];
            #pragma unroll
            for (int dt = 0; dt < 2; ++dt) {
                bf16x8 vbf = *(const bf16x8*)(vbase +
                    (size_t)(dt * 16 + l15) * 384 + kt + l4 * 8);
                oacc[rt][dt] = __builtin_amdgcn_mfma_f32_16x16x32_bf16(
                    pa, vbf, oacc[rt][dt], 0, 0, 0);
            }
        }
    }

    #pragma unroll
    for (int rt = 0; rt < 3; ++rt)
        #pragma unroll
        for (int r = 0; r < 4; ++r) {
            float d = pden[rt][r];
            d += __shfl_xor(d, 1, 64);
            d += __shfl_xor(d, 2, 64);
            d += __shfl_xor(d, 4, 64);
            d += __shfl_xor(d, 8, 64);
            pden[rt][r] = d;
        }

    #pragma unroll
    for (int rt = 0; rt < 3; ++rt) {
        #pragma unroll
        for (int r = 0; r < 4; ++r) {
            float inv = 1.0f / pden[rt][r];
            int qrow = wq0 + rt * 16 + l4 * 4 + r;
            #pragma unroll
            for (int dt = 0; dt < 2; ++dt) {
                size_t off = base + (size_t)qrow * 256 + dt * 16 + l15;
                o[off] = f2bf(oacc[rt][dt][r] * inv * g[off]);
            }
        }
    }
}

extern "C" void kernel_launch(void* const* d_in, const int* in_sizes, int n_in,
                              void* d_out, int out_size, void* d_ws, size_t ws_size,
                              hipStream_t stream) {
    (void)in_sizes; (void)n_in; (void)out_size; (void)ws_size;
    const float* m      = (const float*)d_in[0];
    const float* z      = (const float*)d_in[1];
    const float* mask   = (const float*)d_in[2];
    const float* ln_m_w = (const float*)d_in[3];
    const float* ln_m_b = (const float*)d_in[4];
    const float* ln_z_w = (const float*)d_in[5];
    const float* ln_z_b = (const float*)d_in[6];
    const float* w_z    = (const float*)d_in[7];
    const float* w_q    = (const float*)d_in[8];
    const float* w_k    = (const float*)d_in[9];
    const float* w_v    = (const float*)d_in[10];
    const float* w_g    = (const float*)d_in[11];
    const float* b_g    = (const float*)d_in[12];
    const float* w_o    = (const float*)d_in[13];
    const float* b_o    = (const float*)d_in[14];
    float* out = (float*)d_out;
    char* wsb = (char*)d_ws;

    const size_t NR = (size_t)S * R;  // 49152 rows
    u16*   A   = (u16*)wsb;                      wsb += NR * 256 * 2;
    u16*   q   = (u16*)wsb;                      wsb += NR * 256 * 2;
    u16*   k   = (u16*)wsb;                      wsb += NR * 256 * 2;
    u16*   vT  = (u16*)wsb;                      wsb += NR * 256 * 2;
    u16*   o   = (u16*)wsb;                      wsb += NR * 256 * 2;
    float* g   = (float*)wsb;                    wsb += NR * 256 * 4;
    float* zbT = (float*)wsb;                    wsb += (size_t)H * R * R * 4;
    u16*   Wt  = (u16*)wsb;                      wsb += (size_t)5 * 256 * 256 * 2;

    wprep_kernel<<<5 * 256, 256, 0, stream>>>(w_q, w_k, w_v, w_g, w_o, Wt);
    lnm_kernel<<<NR / 4, 256, 0, stream>>>(m, ln_m_w, ln_m_b, A);
    zbias_kernel<<<2304, 256, 0, stream>>>(z, ln_z_w, ln_z_b, w_z, zbT);
    qkvg_gemm<<<dim3(NR / 128, 4), 512, 0, stream>>>(A, Wt, b_g, q, k, vT, g);
    attn_kernel<<<dim3(H, S), 512, 0, stream>>>(q, k, vT, g, mask, zbT, o);
    out_gemm<<<NR / 128, 512, 0, stream>>>(o, Wt + (size_t)4 * 256 * 256, b_o, out);
}